// Round 5
// baseline (868.491 us; speedup 1.0000x reference)
//
#include <hip/hip_runtime.h>
#include <hip/hip_bf16.h>
#include <stdint.h>

// ---------------------------------------------------------------------------
// PytorchLlamaSDPA: GQA attention (64 q-heads, 8 kv-heads, S=KV=2048, D=128)
// + additive mask (s,t) + softmax + PV + output projection (8192x8192^T).
// bf16 MFMA, fp32 softmax/accum. Attention: 8-warp 32x32 swapped-QK^T,
// P via LDS roundtrip (no cross-lane exchange), V fragments from global.
// ---------------------------------------------------------------------------

typedef __bf16 bf16;
typedef __attribute__((ext_vector_type(8))) __bf16 bf16x8;
typedef __attribute__((ext_vector_type(4))) __bf16 bf16x4;
typedef __attribute__((ext_vector_type(4))) float f32x4;
typedef __attribute__((ext_vector_type(16))) float f32x16;

#define N_HEADS 64
#define N_KVH   8
#define HDIM    128
#define SEQ     2048
#define KVL     2048
#define DIM     8192

__device__ __forceinline__ void gload16(const void* g, void* l) {
  __builtin_amdgcn_global_load_lds((const __attribute__((address_space(1))) void*)g,
                                   (__attribute__((address_space(3))) void*)l,
                                   16, 0, 0);
}

// --------------------------- fp32 -> bf16 (flat) ---------------------------
__global__ void cvt_f32_bf16(const float* __restrict__ in, bf16* __restrict__ out, int n4) {
  int i = blockIdx.x * blockDim.x + threadIdx.x;
  int stride = gridDim.x * blockDim.x;
  for (; i < n4; i += stride) {
    float4 v = ((const float4*)in)[i];
    bf16x4 o = { (bf16)v.x, (bf16)v.y, (bf16)v.z, (bf16)v.w };
    *(bf16x4*)(out + (long)i * 4) = o;
  }
}

// ------------------- values (kh,t,d) -> bf16 V^T (kh,d,t) ------------------
__global__ void cvt_vT_kernel(const float* __restrict__ v, bf16* __restrict__ vT) {
  __shared__ bf16 tile[64][132];
  const int tid = threadIdx.x;
  const int kh = blockIdx.x >> 5;
  const int t0 = (blockIdx.x & 31) << 6;
  const float* src = v + ((long)kh * KVL + t0) * HDIM;
#pragma unroll
  for (int it = 0; it < 8; ++it) {
    int q = it * 256 + tid;
    int r = q >> 5;
    int c4 = (q & 31) << 2;
    float4 val = *(const float4*)(src + (long)r * HDIM + c4);
    bf16x4 o = { (bf16)val.x, (bf16)val.y, (bf16)val.z, (bf16)val.w };
    *(bf16x4*)&tile[r][c4] = o;
  }
  __syncthreads();
  const int t = tid & 63;
  const int dbase = tid >> 6;
#pragma unroll
  for (int it = 0; it < 32; ++it) {
    int d = it * 4 + dbase;
    vT[((long)kh * HDIM + d) * KVL + t0 + t] = tile[t][d];
  }
}

// ------------------------------- attention ---------------------------------
// Grid 512 = 64 heads x 8 q-blocks of 256. Block = 512 threads (8 warps),
// warp owns 32 q-rows. Swapped QK^T: S^T = mfma(K, Q) so lane q = lane&31
// holds a P kv-strip in regs. PV: O^T = mfma(Vfrag_from_global, Pfrag),
// P roundtripped through a per-lane LDS row (bf16, 16B-chunk XOR swizzle).
// LDS: K dbuf 2x16KB at [0,32KB) + P 8 warps x 4KB at [32KB,64KB).
__global__ __launch_bounds__(512, 2) void attn_kernel(
    const bf16* __restrict__ qB, const bf16* __restrict__ kB,
    const bf16* __restrict__ vT, const float* __restrict__ mask,
    bf16* __restrict__ attnB)
{
  __shared__ __align__(16) char lds[65536];

  const int tid  = threadIdx.x;
  const int lane = tid & 63;
  const int w    = tid >> 6;
  const int ihi  = lane >> 5;
  const int l31  = lane & 31;

  // XCD swizzle: kh == bid&7 == XCD id -> each XCD L2 holds one kv-head
  const int bid = blockIdx.x;
  const int swz = (bid & 7) * 64 + (bid >> 3);
  const int h   = swz >> 3;
  const int q0b = (swz & 7) << 8;
  const int kh  = h >> 3;

  // ---- stage Q [256 rows][256B], chunk-swizzled; uses whole 64KB ----
#pragma unroll
  for (int rnd = 0; rnd < 8; ++rnd) {
    int row = rnd * 32 + w * 4 + (lane >> 4);
    int cg  = (lane & 15) ^ (row & 7);
    const bf16* g = qB + (((long)(q0b + row) * N_HEADS + h) << 7) + (cg << 3);
    gload16(g, lds + rnd * 8192 + w * 1024);
  }
  __syncthreads();

  // Q fragments (B-operand: col=q=lane&31, k-slice s: d = 16s + 8*ihi + j)
  bf16x8 qf[8];
  {
    int qrow = (w << 5) + l31;
    const char* qr = lds + qrow * 256;
#pragma unroll
    for (int s = 0; s < 8; ++s)
      qf[s] = *(const bf16x8*)(qr + ((((s << 1) | ihi) ^ (qrow & 7)) << 4));
  }
  __syncthreads();   // Q area freed -> becomes K double buffer + P region

  // ---- stage K tile 0 into buffer 0 ----
#pragma unroll
  for (int rnd = 0; rnd < 2; ++rnd) {
    int row = rnd * 32 + w * 4 + (lane >> 4);
    int cg  = (lane & 15) ^ (row & 7);
    const bf16* g = kB + (((long)(kh * KVL + row)) << 7) + (cg << 3);
    gload16(g, lds + rnd * 8192 + w * 1024);
  }
  __syncthreads();

  const float scale = 0.08838834764831845f;  // 1/sqrt(128)
  const float* mrow = mask + (size_t)(q0b + (w << 5) + l31) * KVL + (ihi << 2);

  // per-lane P row: [64 kv] bf16 = 128B, 8 chunks of 16B, chunk c at c^pkey
  char* pb = lds + 32768 + w * 4096 + l31 * 128;
  const int pkey = l31 & 7;

  f32x16 acc[4];
#pragma unroll
  for (int dt = 0; dt < 4; ++dt) acc[dt] = {};
  float m_run = -1e30f, l_run = 0.f;

  for (int kt = 0; kt < KVL / 64; ++kt) {
    const int cur = kt & 1;
    const int kv0 = kt << 6;
    // ---- issue next K tile into other buffer (drained by end barrier) ----
    if (kt < KVL / 64 - 1) {
      const int kv0n = kv0 + 64;
#pragma unroll
      for (int rnd = 0; rnd < 2; ++rnd) {
        int row = rnd * 32 + w * 4 + (lane >> 4);
        int cg  = (lane & 15) ^ (row & 7);
        const bf16* g = kB + (((long)(kh * KVL + kv0n + row)) << 7) + (cg << 3);
        gload16(g, lds + (cur ^ 1) * 16384 + rnd * 8192 + w * 1024);
      }
    }

    // ---- QK^T (swapped): S^T[kv][q], two 32-kv subtiles ----
    const char* kb = lds + cur * 16384;
    f32x16 s0 = {}, s1 = {};
    const int kr0 = l31, kr1 = 32 + l31;
#pragma unroll
    for (int s = 0; s < 8; ++s) {
      bf16x8 kf0 = *(const bf16x8*)(kb + kr0 * 256 + ((((s << 1) | ihi) ^ (kr0 & 7)) << 4));
      s0 = __builtin_amdgcn_mfma_f32_32x32x16_bf16(kf0, qf[s], s0, 0, 0, 0);
      bf16x8 kf1 = *(const bf16x8*)(kb + kr1 * 256 + ((((s << 1) | ihi) ^ (kr1 & 7)) << 4));
      s1 = __builtin_amdgcn_mfma_f32_32x32x16_bf16(kf1, qf[s], s1, 0, 0, 0);
    }

    // ---- scale + mask; reg r holds kv = (r&3) + 8*(r>>2) + 4*ihi ----
    const float* mrt = mrow + kv0;
    float p0[16], p1[16];
#pragma unroll
    for (int rq = 0; rq < 4; ++rq) {
      f32x4 m0 = *(const f32x4*)(mrt + (rq << 3));
      f32x4 m1 = *(const f32x4*)(mrt + 32 + (rq << 3));
#pragma unroll
      for (int j = 0; j < 4; ++j) {
        p0[rq * 4 + j] = s0[rq * 4 + j] * scale + m0[j];
        p1[rq * 4 + j] = s1[rq * 4 + j] * scale + m1[j];
      }
    }

    // ---- online softmax (per-lane 32 values; one cross-half combine) ----
    float mx = p0[0];
#pragma unroll
    for (int i = 1; i < 16; ++i) mx = fmaxf(mx, p0[i]);
#pragma unroll
    for (int i = 0; i < 16; ++i) mx = fmaxf(mx, p1[i]);
    mx = fmaxf(mx, __shfl_xor(mx, 32));
    float nm = fmaxf(m_run, mx);
    float al = __expf(m_run - nm);
    m_run = nm;
    float ps = 0.f;
#pragma unroll
    for (int i = 0; i < 16; ++i) { p0[i] = __expf(p0[i] - nm); ps += p0[i]; }
#pragma unroll
    for (int i = 0; i < 16; ++i) { p1[i] = __expf(p1[i] - nm); ps += p1[i]; }
    ps += __shfl_xor(ps, 32);
    l_run = l_run * al + ps;
#pragma unroll
    for (int dt = 0; dt < 4; ++dt) acc[dt] *= al;

    // ---- P -> LDS roundtrip (bf16 casts + 8B vector stores, no asm) ----
    // group rq of p0 = kv [8rq+4ihi, +4): octet rq, half ihi. p1: octet 4+rq.
#pragma unroll
    for (int rq = 0; rq < 4; ++rq) {
      bf16x4 v0 = { (bf16)p0[rq * 4 + 0], (bf16)p0[rq * 4 + 1],
                    (bf16)p0[rq * 4 + 2], (bf16)p0[rq * 4 + 3] };
      *(bf16x4*)(pb + ((rq ^ pkey) << 4) + (ihi << 3)) = v0;
      bf16x4 v1 = { (bf16)p1[rq * 4 + 0], (bf16)p1[rq * 4 + 1],
                    (bf16)p1[rq * 4 + 2], (bf16)p1[rq * 4 + 3] };
      *(bf16x4*)(pb + (((4 + rq) ^ pkey) << 4) + (ihi << 3)) = v1;
    }

    // ---- read back P fragments: octet o = 2ks+ihi -> kv [16ks+8ihi, +8) ----
    bf16x8 pfrag[4];
#pragma unroll
    for (int ks = 0; ks < 4; ++ks)
      pfrag[ks] = *(const bf16x8*)(pb + ((((ks << 1) | ihi) ^ pkey) << 4));

    // ---- PV: O^T[d][q] += V^T[d][kv] * P[kv][q]; V direct from global ----
#pragma unroll
    for (int dt = 0; dt < 4; ++dt) {
      const bf16* vg = vT + (size_t)(kh * HDIM + (dt << 5) + l31) * KVL + kv0 + (ihi << 3);
#pragma unroll
      for (int ks = 0; ks < 4; ++ks) {
        bf16x8 vf = *(const bf16x8*)(vg + (ks << 4));
        acc[dt] = __builtin_amdgcn_mfma_f32_32x32x16_bf16(vf, pfrag[ks], acc[dt], 0, 0, 0);
      }
    }
    __syncthreads();
  }

  // ---- epilogue: normalize, LDS transpose, coalesced bf16x8 stores ----
  const float linv = 1.0f / l_run;
  char* ep = lds + (w << 13);   // per-warp 8KB: [32 q][128 d], 256B rows, swizzled
#pragma unroll
  for (int dt = 0; dt < 4; ++dt) {
#pragma unroll
    for (int r = 0; r < 16; ++r) {
      int d = (dt << 5) + (r & 3) + ((r >> 2) << 3) + (ihi << 2);
      int byte = l31 * 256 + (((d >> 3) ^ (l31 & 7)) << 4) + ((d & 7) << 1);
      *(bf16*)(ep + byte) = (bf16)(acc[dt][r] * linv);
    }
  }
  __syncthreads();
  const size_t obase = (size_t)(q0b + (w << 5)) * DIM + h * HDIM;
#pragma unroll
  for (int i = 0; i < 8; ++i) {
    int row = (i << 2) + (lane >> 4);
    int cp  = lane & 15;
    int c   = cp ^ (row & 7);
    bf16x8 ov = *(const bf16x8*)(ep + row * 256 + (cp << 4));
    *(bf16x8*)(attnB + obase + (size_t)row * DIM + (c << 3)) = ov;
  }
}

// ------------------------------ projection GEMM ----------------------------
__global__ __launch_bounds__(256, 2) void gemm_bt(
    const bf16* __restrict__ A, const bf16* __restrict__ B, float* __restrict__ C)
{
  __shared__ __align__(16) bf16 Alds[128 * 64];
  __shared__ __align__(16) bf16 Blds[128 * 64];
  const int tid = threadIdx.x;
  const int lane = tid & 63;
  const int w = tid >> 6;

  const int swz = (blockIdx.x & 7) * 128 + (blockIdx.x >> 3);
  const int m0 = (swz >> 6) << 7;
  const int n0 = (swz & 63) << 7;
  const int wr = (w >> 1) << 6;
  const int wc = (w & 1) << 6;

  f32x4 acc[4][4];
  const f32x4 zero4 = { 0.f, 0.f, 0.f, 0.f };
#pragma unroll
  for (int i = 0; i < 4; ++i)
#pragma unroll
    for (int j = 0; j < 4; ++j) acc[i][j] = zero4;

  for (int kt = 0; kt < DIM / 64; ++kt) {
    const int k0 = kt * 64;
#pragma unroll
    for (int i = 0; i < 4; ++i) {
      int seg = w * 4 + i;
      int m = seg * 8 + (lane >> 3);
      int c = lane & 7;
      const bf16* ga = A + (long)(m0 + m) * DIM + k0 + ((c ^ (m & 7)) << 3);
      gload16(ga, (char*)Alds + seg * 1024);
      const bf16* gb = B + (long)(n0 + m) * DIM + k0 + ((c ^ (m & 7)) << 3);
      gload16(gb, (char*)Blds + seg * 1024);
    }
    __syncthreads();
#pragma unroll
    for (int kc = 0; kc < 2; ++kc) {
      bf16x8 af[4], bfr[4];
#pragma unroll
      for (int i = 0; i < 4; ++i) {
        int m = wr + i * 16 + (lane & 15);
        int c = kc * 4 + (lane >> 4);
        af[i] = *(const bf16x8*)((const char*)Alds + m * 128 + ((c ^ (m & 7)) << 4));
        int n = wc + i * 16 + (lane & 15);
        bfr[i] = *(const bf16x8*)((const char*)Blds + n * 128 + ((c ^ (n & 7)) << 4));
      }
#pragma unroll
      for (int i = 0; i < 4; ++i)
#pragma unroll
        for (int j = 0; j < 4; ++j)
          acc[i][j] = __builtin_amdgcn_mfma_f32_16x16x32_bf16(af[i], bfr[j], acc[i][j], 0, 0, 0);
    }
    __syncthreads();
  }

#pragma unroll
  for (int i = 0; i < 4; ++i) {
#pragma unroll
    for (int r = 0; r < 4; ++r) {
      float* cp = C + (long)(m0 + wr + i * 16 + ((lane >> 4) << 2) + r) * DIM + n0 + wc + (lane & 15);
#pragma unroll
      for (int j = 0; j < 4; ++j)
        cp[j * 16] = acc[i][j][r];
    }
  }
}

// ------------------------------- launcher ----------------------------------
extern "C" void kernel_launch(void* const* d_in, const int* in_sizes, int n_in,
                              void* d_out, int out_size, void* d_ws, size_t ws_size,
                              hipStream_t stream) {
  const float* xq     = (const float*)d_in[0];
  const float* keys   = (const float*)d_in[1];
  const float* values = (const float*)d_in[2];
  const float* mask   = (const float*)d_in[3];
  const float* wo     = (const float*)d_in[4];
  float* out = (float*)d_out;
  char* ws = (char*)d_ws;

  bf16* woB = (bf16*)ws;                                   // 128 MB
  bf16* qB  = (bf16*)(ws + 134217728ull);                  //  32 MB
  bf16* kB  = (bf16*)(ws + 134217728ull + 33554432ull);    //   4 MB
  bf16* vT  = (bf16*)(ws + 134217728ull + 37748736ull);    //   4 MB
  bf16* aB  = (bf16*)(ws + 134217728ull + 41943040ull);    //  32 MB

  cvt_f32_bf16<<<dim3(2048), dim3(256), 0, stream>>>(wo, woB, 16777216);
  cvt_f32_bf16<<<dim3(1024), dim3(256), 0, stream>>>(xq, qB, 4194304);
  cvt_f32_bf16<<<dim3(256),  dim3(256), 0, stream>>>(keys, kB, 524288);
  cvt_vT_kernel<<<dim3(256), dim3(256), 0, stream>>>(values, vT);
  attn_kernel<<<dim3(512),   dim3(512), 0, stream>>>(qB, kB, vT, mask, aB);
  gemm_bt<<<dim3(1024),      dim3(256), 0, stream>>>(aB, woB, out);
}

// Round 6
// 671.104 us; speedup vs baseline: 1.2941x; 1.2941x over previous
//
#include <hip/hip_runtime.h>
#include <hip/hip_bf16.h>
#include <stdint.h>

// ---------------------------------------------------------------------------
// PytorchLlamaSDPA: GQA attention (64 q-heads, 8 kv-heads, S=KV=2048, D=128)
// + additive mask (s,t) + softmax + PV + output projection (8192x8192^T).
// bf16 MFMA, fp32 softmax/accum. Attention: 8-warp 32x32 swapped-QK^T,
// K+V LDS double-buffered, P via in-register exchange (manual bf16 pack).
// ---------------------------------------------------------------------------

typedef __bf16 bf16;
typedef __attribute__((ext_vector_type(8))) __bf16 bf16x8;
typedef __attribute__((ext_vector_type(4))) __bf16 bf16x4;
typedef __attribute__((ext_vector_type(4))) float f32x4;
typedef __attribute__((ext_vector_type(16))) float f32x16;
typedef __attribute__((ext_vector_type(4))) unsigned int u32x4;

#define N_HEADS 64
#define N_KVH   8
#define HDIM    128
#define SEQ     2048
#define KVL     2048
#define DIM     8192

__device__ __forceinline__ void gload16(const void* g, void* l) {
  __builtin_amdgcn_global_load_lds((const __attribute__((address_space(1))) void*)g,
                                   (__attribute__((address_space(3))) void*)l,
                                   16, 0, 0);
}

// pack two floats to one u32 of two bf16 (lo in bits 15:0) - pure bit ops
__device__ __forceinline__ unsigned pack2(float lo, float hi) {
  union { bf16 h; unsigned short u; } a, b;
  a.h = (bf16)lo; b.h = (bf16)hi;
  return ((unsigned)b.u << 16) | (unsigned)a.u;
}

// cross-half exchange: r0 = lane<32 ? a : partner(b); r1 = lane<32 ? partner(a) : b
__device__ __forceinline__ void exch(unsigned a, unsigned b, bool hi, unsigned& r0, unsigned& r1) {
  unsigned sa = (unsigned)__shfl_xor((int)a, 32);
  unsigned sb = (unsigned)__shfl_xor((int)b, 32);
  r0 = hi ? sb : a;
  r1 = hi ? b  : sa;
}

// Build two PV B-operand fragments (kv-slices of 16) from one 32-kv P strip.
// p[r] holds P at kv = (r&3) + 8*(r>>2) + 4*ihi for this lane's q = lane&31.
__device__ __forceinline__ void buildfrags(const float (&p)[16], bool hi, bf16x8& f0, bf16x8& f1) {
  unsigned pk0 = pack2(p[0],  p[1]),  pk1 = pack2(p[2],  p[3]);
  unsigned pk2 = pack2(p[4],  p[5]),  pk3 = pack2(p[6],  p[7]);
  unsigned pk4 = pack2(p[8],  p[9]),  pk5 = pack2(p[10], p[11]);
  unsigned pk6 = pack2(p[12], p[13]), pk7 = pack2(p[14], p[15]);
  unsigned a0, a1, b0, b1, c0, c1, d0, d1;
  exch(pk0, pk2, hi, a0, a1);
  exch(pk1, pk3, hi, b0, b1);
  exch(pk4, pk6, hi, c0, c1);
  exch(pk5, pk7, hi, d0, d1);
  u32x4 w0 = { a0, b0, a1, b1 };
  u32x4 w1 = { c0, d0, c1, d1 };
  f0 = __builtin_bit_cast(bf16x8, w0);
  f1 = __builtin_bit_cast(bf16x8, w1);
}

// --------------------------- fp32 -> bf16 (flat) ---------------------------
__global__ void cvt_f32_bf16(const float* __restrict__ in, bf16* __restrict__ out, int n4) {
  int i = blockIdx.x * blockDim.x + threadIdx.x;
  int stride = gridDim.x * blockDim.x;
  for (; i < n4; i += stride) {
    float4 v = ((const float4*)in)[i];
    bf16x4 o = { (bf16)v.x, (bf16)v.y, (bf16)v.z, (bf16)v.w };
    *(bf16x4*)(out + (long)i * 4) = o;
  }
}

// ------------------- values (kh,t,d) -> bf16 V^T (kh,d,t) ------------------
__global__ void cvt_vT_kernel(const float* __restrict__ v, bf16* __restrict__ vT) {
  __shared__ bf16 tile[64][132];
  const int tid = threadIdx.x;
  const int kh = blockIdx.x >> 5;
  const int t0 = (blockIdx.x & 31) << 6;
  const float* src = v + ((long)kh * KVL + t0) * HDIM;
#pragma unroll
  for (int it = 0; it < 8; ++it) {
    int q = it * 256 + tid;
    int r = q >> 5;
    int c4 = (q & 31) << 2;
    float4 val = *(const float4*)(src + (long)r * HDIM + c4);
    bf16x4 o = { (bf16)val.x, (bf16)val.y, (bf16)val.z, (bf16)val.w };
    *(bf16x4*)&tile[r][c4] = o;
  }
  __syncthreads();
  const int t = tid & 63;
  const int dbase = tid >> 6;
#pragma unroll
  for (int it = 0; it < 32; ++it) {
    int d = it * 4 + dbase;
    vT[((long)kh * HDIM + d) * KVL + t0 + t] = tile[t][d];
  }
}

// ------------------------------- attention ---------------------------------
// Grid 512 = 64 heads x 8 q-blocks of 256. Block = 512 threads (8 warps),
// warp owns 32 q-rows. Swapped QK^T: S^T = mfma(K, Q) so lane q = lane&31
// holds a P kv-strip in regs; softmax fully in-register; P fragments built
// by manual bf16 pack + one cross-half shuffle per word pair.
// PV: O^T = mfma(Vfrag, Pfrag) with V^T staged in LDS.
// LDS (64KB): K dbuf 2x16KB at [0,32KB) + V^T dbuf 2x16KB at [32KB,64KB).
// Block mapping: identity. bid&7 = q-block index = XCD -> each XCD's L2
// holds one 2MB mask slice (the dominant stream).
__global__ __launch_bounds__(512, 2) void attn_kernel(
    const bf16* __restrict__ qB, const bf16* __restrict__ kB,
    const bf16* __restrict__ vT, const float* __restrict__ mask,
    bf16* __restrict__ attnB)
{
  __shared__ __align__(16) char lds[65536];

  const int tid  = threadIdx.x;
  const int lane = tid & 63;
  const int w    = tid >> 6;
  const bool hi  = (lane >> 5) != 0;
  const int ihi  = lane >> 5;
  const int l31  = lane & 31;

  const int bid = blockIdx.x;
  const int h   = bid >> 3;
  const int q0b = (bid & 7) << 8;
  const int kh  = h >> 3;

  // ---- stage Q [256 rows][256B], chunk-swizzled; uses whole 64KB ----
#pragma unroll
  for (int rnd = 0; rnd < 8; ++rnd) {
    int row = rnd * 32 + w * 4 + (lane >> 4);
    int cg  = (lane & 15) ^ (row & 7);
    const bf16* g = qB + (((long)(q0b + row) * N_HEADS + h) << 7) + (cg << 3);
    gload16(g, lds + rnd * 8192 + w * 1024);
  }
  __syncthreads();

  // Q fragments (B-operand: col=q=lane&31, k-slice s: d = 16s + 8*ihi + j)
  bf16x8 qf[8];
  {
    int qrow = (w << 5) + l31;
    const char* qr = lds + qrow * 256;
#pragma unroll
    for (int s = 0; s < 8; ++s)
      qf[s] = *(const bf16x8*)(qr + ((((s << 1) | ihi) ^ (qrow & 7)) << 4));
  }
  __syncthreads();   // Q area freed -> becomes K/V double buffers

  // ---- stage K/V tile 0 into buffer 0 ----
  {
#pragma unroll
    for (int rnd = 0; rnd < 2; ++rnd) {
      int row = rnd * 32 + w * 4 + (lane >> 4);
      int cg  = (lane & 15) ^ (row & 7);
      const bf16* g = kB + (((long)(kh * KVL + row)) << 7) + (cg << 3);
      gload16(g, lds + rnd * 8192 + w * 1024);
    }
#pragma unroll
    for (int rnd = 0; rnd < 2; ++rnd) {
      int row = rnd * 64 + w * 8 + (lane >> 3);   // row = d, 128B rows
      int cg  = (lane & 7) ^ (row & 7);
      const bf16* g = vT + ((long)(kh * HDIM + row) * KVL) + (cg << 3);
      gload16(g, lds + 32768 + rnd * 8192 + w * 1024);
    }
  }
  __syncthreads();

  const float scale = 0.08838834764831845f;  // 1/sqrt(128)
  const float* mrow = mask + (size_t)(q0b + (w << 5) + l31) * KVL + (ihi << 2);

  f32x16 acc[4];
#pragma unroll
  for (int dt = 0; dt < 4; ++dt) acc[dt] = {};
  float m_run = -1e30f, l_run = 0.f;

  for (int kt = 0; kt < KVL / 64; ++kt) {
    const int cur = kt & 1;
    const int kv0 = kt << 6;

    // ---- issue next-tile K/V stage into other buffers (before compute) ----
    if (kt < KVL / 64 - 1) {
      const int kv0n = kv0 + 64;
#pragma unroll
      for (int rnd = 0; rnd < 2; ++rnd) {
        int row = rnd * 32 + w * 4 + (lane >> 4);
        int cg  = (lane & 15) ^ (row & 7);
        const bf16* g = kB + (((long)(kh * KVL + kv0n + row)) << 7) + (cg << 3);
        gload16(g, lds + (cur ^ 1) * 16384 + rnd * 8192 + w * 1024);
      }
#pragma unroll
      for (int rnd = 0; rnd < 2; ++rnd) {
        int row = rnd * 64 + w * 8 + (lane >> 3);
        int cg  = (lane & 7) ^ (row & 7);
        const bf16* g = vT + ((long)(kh * HDIM + row) * KVL) + kv0n + (cg << 3);
        gload16(g, lds + 32768 + (cur ^ 1) * 16384 + rnd * 8192 + w * 1024);
      }
    }

    // ---- mask prefetch (issued before QK^T; consumed after) ----
    const float* mrt = mrow + kv0;
    f32x4 mk0[4], mk1[4];
#pragma unroll
    for (int rq = 0; rq < 4; ++rq) {
      mk0[rq] = *(const f32x4*)(mrt + (rq << 3));
      mk1[rq] = *(const f32x4*)(mrt + 32 + (rq << 3));
    }

    // ---- QK^T (swapped): S^T[kv][q], two 32-kv subtiles ----
    const char* kb = lds + cur * 16384;
    f32x16 s0 = {}, s1 = {};
    const int kr0 = l31, kr1 = 32 + l31;
#pragma unroll
    for (int s = 0; s < 8; ++s) {
      bf16x8 kf0 = *(const bf16x8*)(kb + kr0 * 256 + ((((s << 1) | ihi) ^ (kr0 & 7)) << 4));
      s0 = __builtin_amdgcn_mfma_f32_32x32x16_bf16(kf0, qf[s], s0, 0, 0, 0);
      bf16x8 kf1 = *(const bf16x8*)(kb + kr1 * 256 + ((((s << 1) | ihi) ^ (kr1 & 7)) << 4));
      s1 = __builtin_amdgcn_mfma_f32_32x32x16_bf16(kf1, qf[s], s1, 0, 0, 0);
    }

    // ---- scale + mask; reg r holds kv = (r&3) + 8*(r>>2) + 4*ihi ----
    float p0[16], p1[16];
#pragma unroll
    for (int rq = 0; rq < 4; ++rq) {
#pragma unroll
      for (int j = 0; j < 4; ++j) {
        p0[rq * 4 + j] = s0[rq * 4 + j] * scale + mk0[rq][j];
        p1[rq * 4 + j] = s1[rq * 4 + j] * scale + mk1[rq][j];
      }
    }

    // ---- online softmax (per-lane 32 values; one cross-half combine) ----
    float mx = p0[0];
#pragma unroll
    for (int i = 1; i < 16; ++i) mx = fmaxf(mx, p0[i]);
#pragma unroll
    for (int i = 0; i < 16; ++i) mx = fmaxf(mx, p1[i]);
    mx = fmaxf(mx, __shfl_xor(mx, 32));
    float nm = fmaxf(m_run, mx);
    float al = __expf(m_run - nm);
    m_run = nm;
    float ps = 0.f;
#pragma unroll
    for (int i = 0; i < 16; ++i) { p0[i] = __expf(p0[i] - nm); ps += p0[i]; }
#pragma unroll
    for (int i = 0; i < 16; ++i) { p1[i] = __expf(p1[i] - nm); ps += p1[i]; }
    ps += __shfl_xor(ps, 32);
    l_run = l_run * al + ps;
#pragma unroll
    for (int dt = 0; dt < 4; ++dt) acc[dt] *= al;

    // ---- P -> bf16 B-fragments (manual pack + cross-half exchange) ----
    bf16x8 pfrag[4];
    buildfrags(p0, hi, pfrag[0], pfrag[1]);
    buildfrags(p1, hi, pfrag[2], pfrag[3]);

    // ---- PV: O^T[d][q] += V^T[d][kv] * P[kv][q]; V from LDS ----
    const char* vb = lds + 32768 + cur * 16384;
#pragma unroll
    for (int dt = 0; dt < 4; ++dt) {
      const int vrow = (dt << 5) + l31;
      const char* vrp = vb + vrow * 128;
#pragma unroll
      for (int ks = 0; ks < 4; ++ks) {
        bf16x8 vf = *(const bf16x8*)(vrp + ((((ks << 1) | ihi) ^ (vrow & 7)) << 4));
        acc[dt] = __builtin_amdgcn_mfma_f32_32x32x16_bf16(vf, pfrag[ks], acc[dt], 0, 0, 0);
      }
    }
    __syncthreads();
  }

  // ---- epilogue: normalize, LDS transpose, coalesced bf16x8 stores ----
  const float linv = 1.0f / l_run;
  char* ep = lds + (w << 13);   // per-warp 8KB: [32 q][128 d], 256B rows, swizzled
#pragma unroll
  for (int dt = 0; dt < 4; ++dt) {
#pragma unroll
    for (int r = 0; r < 16; ++r) {
      int d = (dt << 5) + (r & 3) + ((r >> 2) << 3) + (ihi << 2);
      int byte = l31 * 256 + (((d >> 3) ^ (l31 & 7)) << 4) + ((d & 7) << 1);
      *(bf16*)(ep + byte) = (bf16)(acc[dt][r] * linv);
    }
  }
  __syncthreads();
  const size_t obase = (size_t)(q0b + (w << 5)) * DIM + h * HDIM;
#pragma unroll
  for (int i = 0; i < 8; ++i) {
    int row = (i << 2) + (lane >> 4);
    int cp  = lane & 15;
    int c   = cp ^ (row & 7);
    bf16x8 ov = *(const bf16x8*)(ep + row * 256 + (cp << 4));
    *(bf16x8*)(attnB + obase + (size_t)row * DIM + (c << 3)) = ov;
  }
}

// ------------------------------ projection GEMM ----------------------------
__global__ __launch_bounds__(256, 2) void gemm_bt(
    const bf16* __restrict__ A, const bf16* __restrict__ B, float* __restrict__ C)
{
  __shared__ __align__(16) bf16 Alds[128 * 64];
  __shared__ __align__(16) bf16 Blds[128 * 64];
  const int tid = threadIdx.x;
  const int lane = tid & 63;
  const int w = tid >> 6;

  const int swz = (blockIdx.x & 7) * 128 + (blockIdx.x >> 3);
  const int m0 = (swz >> 6) << 7;
  const int n0 = (swz & 63) << 7;
  const int wr = (w >> 1) << 6;
  const int wc = (w & 1) << 6;

  f32x4 acc[4][4];
  const f32x4 zero4 = { 0.f, 0.f, 0.f, 0.f };
#pragma unroll
  for (int i = 0; i < 4; ++i)
#pragma unroll
    for (int j = 0; j < 4; ++j) acc[i][j] = zero4;

  for (int kt = 0; kt < DIM / 64; ++kt) {
    const int k0 = kt * 64;
#pragma unroll
    for (int i = 0; i < 4; ++i) {
      int seg = w * 4 + i;
      int m = seg * 8 + (lane >> 3);
      int c = lane & 7;
      const bf16* ga = A + (long)(m0 + m) * DIM + k0 + ((c ^ (m & 7)) << 3);
      gload16(ga, (char*)Alds + seg * 1024);
      const bf16* gb = B + (long)(n0 + m) * DIM + k0 + ((c ^ (m & 7)) << 3);
      gload16(gb, (char*)Blds + seg * 1024);
    }
    __syncthreads();
#pragma unroll
    for (int kc = 0; kc < 2; ++kc) {
      bf16x8 af[4], bfr[4];
#pragma unroll
      for (int i = 0; i < 4; ++i) {
        int m = wr + i * 16 + (lane & 15);
        int c = kc * 4 + (lane >> 4);
        af[i] = *(const bf16x8*)((const char*)Alds + m * 128 + ((c ^ (m & 7)) << 4));
        int n = wc + i * 16 + (lane & 15);
        bfr[i] = *(const bf16x8*)((const char*)Blds + n * 128 + ((c ^ (n & 7)) << 4));
      }
#pragma unroll
      for (int i = 0; i < 4; ++i)
#pragma unroll
        for (int j = 0; j < 4; ++j)
          acc[i][j] = __builtin_amdgcn_mfma_f32_16x16x32_bf16(af[i], bfr[j], acc[i][j], 0, 0, 0);
    }
    __syncthreads();
  }

#pragma unroll
  for (int i = 0; i < 4; ++i) {
#pragma unroll
    for (int r = 0; r < 4; ++r) {
      float* cp = C + (long)(m0 + wr + i * 16 + ((lane >> 4) << 2) + r) * DIM + n0 + wc + (lane & 15);
#pragma unroll
      for (int j = 0; j < 4; ++j)
        cp[j * 16] = acc[i][j][r];
    }
  }
}

// ------------------------------- launcher ----------------------------------
extern "C" void kernel_launch(void* const* d_in, const int* in_sizes, int n_in,
                              void* d_out, int out_size, void* d_ws, size_t ws_size,
                              hipStream_t stream) {
  const float* xq     = (const float*)d_in[0];
  const float* keys   = (const float*)d_in[1];
  const float* values = (const float*)d_in[2];
  const float* mask   = (const float*)d_in[3];
  const float* wo     = (const float*)d_in[4];
  float* out = (float*)d_out;
  char* ws = (char*)d_ws;

  bf16* woB = (bf16*)ws;                                   // 128 MB
  bf16* qB  = (bf16*)(ws + 134217728ull);                  //  32 MB
  bf16* kB  = (bf16*)(ws + 134217728ull + 33554432ull);    //   4 MB
  bf16* vT  = (bf16*)(ws + 134217728ull + 37748736ull);    //   4 MB
  bf16* aB  = (bf16*)(ws + 134217728ull + 41943040ull);    //  32 MB

  cvt_f32_bf16<<<dim3(2048), dim3(256), 0, stream>>>(wo, woB, 16777216);
  cvt_f32_bf16<<<dim3(1024), dim3(256), 0, stream>>>(xq, qB, 4194304);
  cvt_f32_bf16<<<dim3(256),  dim3(256), 0, stream>>>(keys, kB, 524288);
  cvt_vT_kernel<<<dim3(256), dim3(256), 0, stream>>>(values, vT);
  attn_kernel<<<dim3(512),   dim3(512), 0, stream>>>(qB, kB, vT, mask, aB);
  gemm_bt<<<dim3(1024),      dim3(256), 0, stream>>>(aB, woB, out);
}